// Round 3
// baseline (433.762 us; speedup 1.0000x reference)
//
#include <hip/hip_runtime.h>
#include <hip/hip_bf16.h>

// Problem: NX=128, NU=64, NY=32, N=262144. Inputs fp32, output fp32 (proven R1/R2:
// bf16-interp of inputs -> NaN; bf16-packed output -> sqrt(2)*max error signature).
// dx = x@A^T + u@B^T ; y = x@C^T
// A=(-0.5(Q+G^TG+eps I)+S)@P ; B=sqrtm(Q)@(H/(1.01*sqrt(lmax(HH^T)))) ; C=G@P
// Pack W[160][192] = [A|B ; C|0] bf16; one HBM-bound MFMA GEMM over N, fp32 out.
// sqrtm via degree-32 Chebyshev of sqrt applied to Htilde (B-term small vs dx ~400).

#define NB 262144

typedef __attribute__((ext_vector_type(8))) short s8v;
typedef __attribute__((ext_vector_type(4))) short s4v;
typedef __attribute__((ext_vector_type(4))) float f4v;

__device__ __forceinline__ float bf2f(unsigned short s) {
  unsigned int u = ((unsigned int)s) << 16;
  return __uint_as_float(u);
}
__device__ __forceinline__ unsigned short f2bf(float f) {
  unsigned int u = __float_as_uint(f);
  u += 0x7fffu + ((u >> 16) & 1u);
  return (unsigned short)(u >> 16);
}

// ---------------- prep1: M = -0.5(Q+G^TG+eps I)+S (fp32), HtH (fp32), W zero pad ----------------
__global__ __launch_bounds__(256) void k_prep1(
    const float* __restrict__ Q, const float* __restrict__ S,
    const float* __restrict__ G, const float* __restrict__ H,
    float* __restrict__ Mf, float* __restrict__ HtH, unsigned short* __restrict__ W)
{
  const int bid = blockIdx.x, tid = threadIdx.x;
  if (bid < 64) {
    const int idx = bid * 256 + tid;
    const int j = idx >> 7, k = idx & 127;
    float g = 0.f;
    #pragma unroll 4
    for (int i = 0; i < 32; ++i)
      g += G[i * 128 + j] * G[i * 128 + k];
    Mf[idx] = -0.5f * (Q[idx] + g + ((j == k) ? 1e-4f : 0.f)) + S[idx];
  } else {
    const int e = (bid - 64) * 256 + tid;  // 0..4095
    const int a = e >> 6, b = e & 63;
    float s = 0.f;
    #pragma unroll 4
    for (int r = 0; r < 128; ++r)
      s += H[r * 64 + a] * H[r * 64 + b];
    HtH[e] = s;
    if (bid == 64) {
      for (int i = 0; i < 8; ++i) {
        int e2 = i * 256 + tid;  // 0..2047
        int n = 128 + (e2 >> 6), kk = 128 + (e2 & 63);
        W[n * 192 + kk] = 0;
      }
    }
  }
}

// ---------------- prepAC: A = M@P, C = G@P -> W (bf16) ----------------
__global__ __launch_bounds__(256) void k_prepAC(
    const float* __restrict__ Mf, const float* __restrict__ P,
    const float* __restrict__ G, unsigned short* __restrict__ W)
{
  const int bid = blockIdx.x, tid = threadIdx.x;
  if (bid < 64) {
    const int idx = bid * 256 + tid;
    const int n = idx >> 7, k = idx & 127;
    float s = 0.f;
    #pragma unroll 4
    for (int l = 0; l < 128; ++l)
      s += Mf[n * 128 + l] * P[l * 128 + k];
    W[n * 192 + k] = f2bf(s);
  } else {
    for (int i = 0; i < 4; ++i) {
      int e = (bid - 64) * 1024 + i * 256 + tid;  // 0..4095
      int j = e >> 7, k = e & 127;
      float s = 0.f;
      #pragma unroll 4
      for (int l = 0; l < 128; ++l)
        s += G[j * 128 + l] * P[l * 128 + k];
      W[(128 + j) * 192 + k] = f2bf(s);
    }
  }
}

// ---------------- prep23: power iterations + Chebyshev sqrtm(Q)@Htilde -> W B-part ----------------
__global__ __launch_bounds__(1024) void k_prep23(
    const float* __restrict__ Qg, const float* __restrict__ Hg,
    const float* __restrict__ HtHg, unsigned short* __restrict__ W)
{
  __shared__ char smem[65536];
  unsigned short* Xs = (unsigned short*)smem;            // [0,32768): 128x128 swizzled
  unsigned short* V0s = (unsigned short*)(smem + 32768); // 64x128 swizzled (V^T)
  unsigned short* V1s = (unsigned short*)(smem + 49152);
  float* vQ = (float*)(smem + 32768);   // overlap V region (phases A/B only)
  float* wQ = (float*)(smem + 33280);
  float* vH = (float*)(smem + 33792);
  float* wH = (float*)(smem + 34048);
  float* red = (float*)(smem + 34304);
  float* HtHs = (float*)(smem + 49152); // overlaps V1s (phases A/B only)

  const int tid = threadIdx.x;
  const int lane = tid & 63;
  const int wv = tid >> 6;

  // load Q -> Xs (swizzled: logical chunk c of row m stored at chunk c ^ (m&7))
  for (int i = 0; i < 16; ++i) {
    int e = i * 1024 + tid;
    int m = e >> 7, k = e & 127;
    Xs[m * 128 + (((k >> 3) ^ (m & 7)) << 3) + (k & 7)] = f2bf(Qg[e]);
  }
  for (int i = 0; i < 4; ++i) HtHs[i * 1024 + tid] = HtHg[i * 1024 + tid];
  if (tid < 128) vQ[tid] = (float)((tid * 1103515245u + 12345u) & 0xffffu) * (1.f / 65536.f) + 0.05f;
  if (tid < 64)  vH[tid] = (float)((tid * 2654435761u + 911u) & 0xffffu) * (1.f / 65536.f) + 0.05f;
  __syncthreads();

  // ---- phase A: power iteration on Q (24 iters) -> lamQ ----
  float lamQ = 1.f;
  {
    const int row = tid >> 3, sub = tid & 7;
    for (int it = 0; it < 24; ++it) {
      const s8v q0 = *(const s8v*)&Xs[row * 128 + ((((sub * 2)    ) ^ (row & 7)) << 3)];
      const s8v q1 = *(const s8v*)&Xs[row * 128 + ((((sub * 2) + 1) ^ (row & 7)) << 3)];
      float p = 0.f;
      #pragma unroll
      for (int j = 0; j < 8; ++j) p += bf2f((unsigned short)q0[j]) * vQ[sub * 16 + j];
      #pragma unroll
      for (int j = 0; j < 8; ++j) p += bf2f((unsigned short)q1[j]) * vQ[sub * 16 + 8 + j];
      p += __shfl_xor(p, 1); p += __shfl_xor(p, 2); p += __shfl_xor(p, 4);
      if (sub == 0) wQ[row] = p;
      __syncthreads();
      if (tid < 64) {
        float s = wQ[tid] * wQ[tid] + wQ[tid + 64] * wQ[tid + 64];
        s += __shfl_xor(s, 1); s += __shfl_xor(s, 2); s += __shfl_xor(s, 4);
        s += __shfl_xor(s, 8); s += __shfl_xor(s, 16); s += __shfl_xor(s, 32);
        if (tid == 0) red[0] = sqrtf(s);
      }
      __syncthreads();
      lamQ = red[0];
      if (tid < 128) vQ[tid] = wQ[tid] / lamQ;
      __syncthreads();
    }
  }
  const float bb = 1.10f * lamQ;   // Chebyshev interval [0, bb]
  const float sqrtb = sqrtf(bb);

  // ---- phase B: power iteration on HtH (24 iters) -> lamH ----
  float lamH = 1.f;
  {
    const int row = tid >> 4, sub = tid & 15;
    for (int it = 0; it < 24; ++it) {
      const f4v h = *(const f4v*)&HtHs[row * 64 + sub * 4];
      float p = h[0] * vH[sub * 4] + h[1] * vH[sub * 4 + 1] + h[2] * vH[sub * 4 + 2] + h[3] * vH[sub * 4 + 3];
      p += __shfl_xor(p, 1); p += __shfl_xor(p, 2); p += __shfl_xor(p, 4); p += __shfl_xor(p, 8);
      if (sub == 0) wH[row] = p;
      __syncthreads();
      if (tid < 64) {
        float s = wH[tid] * wH[tid];
        s += __shfl_xor(s, 1); s += __shfl_xor(s, 2); s += __shfl_xor(s, 4);
        s += __shfl_xor(s, 8); s += __shfl_xor(s, 16); s += __shfl_xor(s, 32);
        if (tid == 0) red[0] = sqrtf(s);
      }
      __syncthreads();
      lamH = red[0];
      if (tid < 64) vH[tid] = wH[tid] / lamH;
      __syncthreads();
    }
  }
  const float invden = 1.f / (1.01f * sqrtf(lamH));
  __syncthreads();

  // ---- phase C: X = (2/b)Q - I in place; V0 = Htilde^T; Chebyshev recurrence ----
  for (int i = 0; i < 16; ++i) {
    int e = i * 1024 + tid;
    int m = e >> 7, k = e & 127;
    int a = m * 128 + (((k >> 3) ^ (m & 7)) << 3) + (k & 7);
    float q = bf2f(Xs[a]);
    Xs[a] = f2bf(q * (2.f / bb) - ((m == k) ? 1.f : 0.f));
  }
  for (int i = 0; i < 8; ++i) {
    int e = i * 1024 + tid;
    int j = e & 63, m = e >> 6;
    V0s[j * 128 + (((m >> 3) ^ (j & 7)) << 3) + (m & 7)] = f2bf(Hg[m * 64 + j] * invden);
  }
  const int t0 = wv * 2;   // 2 of 32 16x16 tiles per wave (8 m-tiles x 4 n-tiles)
  float baccR[2][4];
  #pragma unroll
  for (int tt = 0; tt < 2; ++tt) {
    int mt = (t0 + tt) >> 2, nt = (t0 + tt) & 3;
    int n = nt * 16 + (lane & 15);
    int mb = mt * 16 + ((lane >> 4) << 2);
    #pragma unroll
    for (int i = 0; i < 4; ++i)
      baccR[tt][i] = 0.63661977f * Hg[(mb + i) * 64 + n] * invden;  // a0 * T0 term
  }
  __syncthreads();

  unsigned short* Vc = V0s;
  unsigned short* Vp = V1s;
  for (int k = 1; k <= 32; ++k) {
    const float ck = ((k & 1) ? 1.0f : -1.0f) / (3.14159265f * ((float)(k * k) - 0.25f));
    #pragma unroll
    for (int tt = 0; tt < 2; ++tt) {
      const int mt = (t0 + tt) >> 2, nt = (t0 + tt) & 3;
      f4v acc = {0.f, 0.f, 0.f, 0.f};
      const int arow = mt * 16 + (lane & 15);
      const int brow = nt * 16 + (lane & 15);
      #pragma unroll
      for (int ks = 0; ks < 4; ++ks) {
        int kc = ks * 4 + (lane >> 4);
        s8v af = *(const s8v*)&Xs[arow * 128 + ((kc ^ (arow & 7)) << 3)];
        s8v bf = *(const s8v*)&Vc[brow * 128 + ((kc ^ (brow & 7)) << 3)];
        acc = __builtin_amdgcn_mfma_f32_16x16x32_bf16(af, bf, acc, 0, 0, 0);
      }
      const int n = brow;
      const int mb = mt * 16 + ((lane >> 4) << 2);
      const int vaddr = n * 128 + (((mb >> 3) ^ (n & 7)) << 3) + (mb & 7);
      float nv[4];
      if (k == 1) {
        #pragma unroll
        for (int i = 0; i < 4; ++i) nv[i] = acc[i];
      } else {
        s4v ov = *(const s4v*)&Vp[vaddr];
        #pragma unroll
        for (int i = 0; i < 4; ++i) nv[i] = 2.f * acc[i] - bf2f((unsigned short)ov[i]);
      }
      s4v st;
      #pragma unroll
      for (int i = 0; i < 4; ++i) { st[i] = (short)f2bf(nv[i]); baccR[tt][i] += ck * nv[i]; }
      *(s4v*)&Vp[vaddr] = st;
    }
    __syncthreads();
    unsigned short* t = Vc; Vc = Vp; Vp = t;
  }

  // ---- phase D: B = sqrt(b) * sum -> W[m][128+j] ----
  #pragma unroll
  for (int tt = 0; tt < 2; ++tt) {
    const int mt = (t0 + tt) >> 2, nt = (t0 + tt) & 3;
    const int n = nt * 16 + (lane & 15);
    const int mb = mt * 16 + ((lane >> 4) << 2);
    #pragma unroll
    for (int i = 0; i < 4; ++i)
      W[(mb + i) * 192 + 128 + n] = f2bf(sqrtb * baccR[tt][i]);
  }
}

// ---------------- main: Out[N][160] = [x|u] @ W^T ; fp32 in, fp32 out ----------------
__global__ __launch_bounds__(256, 2) void k_main(
    const float* __restrict__ x, const float* __restrict__ u,
    const unsigned short* __restrict__ W, float* __restrict__ out)
{
  __shared__ char smraw[128 * 200 * 2];          // 51200 B
  unsigned short* sm = (unsigned short*)smraw;    // staging: [128 rows][200], cols 0..127 x, 128..191 u
  float* fb = (float*)smraw;                      // epilogue reuse: [64 rows][164] fp32 = 41984 B

  const int tid = threadIdx.x, lane = tid & 63, w = tid >> 6;
  const int mw = w & 1, nw = w >> 1;
  const int base = blockIdx.x * 128;

  // weight fragments: this wave's 5 n-tiles x 6 k-steps, registers for whole block
  s8v wf[5][6];
  {
    const int n0 = nw * 80 + (lane & 15);
    const int kof = (lane >> 4) * 8;
    #pragma unroll
    for (int nt = 0; nt < 5; ++nt)
      #pragma unroll
      for (int ks = 0; ks < 6; ++ks)
        wf[nt][ks] = *(const s8v*)&W[(n0 + nt * 16) * 192 + ks * 32 + kof];
  }
  // stage x,u tiles: fp32 16B loads, convert to bf16
  #pragma unroll
  for (int p = 0; p < 16; ++p) {
    int g = p * 256 + tid; int r = g >> 5, c = g & 31;
    f4v v = *(const f4v*)&x[(size_t)(base + r) * 128 + c * 4];
    s4v b;
    #pragma unroll
    for (int i = 0; i < 4; ++i) b[i] = (short)f2bf(v[i]);
    *(s4v*)&sm[r * 200 + c * 4] = b;
  }
  #pragma unroll
  for (int p = 0; p < 8; ++p) {
    int g = p * 256 + tid; int r = g >> 4, c = g & 15;
    f4v v = *(const f4v*)&u[(size_t)(base + r) * 64 + c * 4];
    s4v b;
    #pragma unroll
    for (int i = 0; i < 4; ++i) b[i] = (short)f2bf(v[i]);
    *(s4v*)&sm[r * 200 + 128 + c * 4] = b;
  }
  __syncthreads();

  f4v acc[4][5];
  #pragma unroll
  for (int mt = 0; mt < 4; ++mt)
    #pragma unroll
    for (int nt = 0; nt < 5; ++nt)
      acc[mt][nt] = (f4v){0.f, 0.f, 0.f, 0.f};

  #pragma unroll
  for (int mt = 0; mt < 4; ++mt) {
    const int row = mw * 64 + mt * 16 + (lane & 15);
    const int kof = (lane >> 4) * 8;
    #pragma unroll
    for (int ks = 0; ks < 6; ++ks) {
      s8v af = *(const s8v*)&sm[row * 200 + ks * 32 + kof];
      #pragma unroll
      for (int nt = 0; nt < 5; ++nt)
        acc[mt][nt] = __builtin_amdgcn_mfma_f32_16x16x32_bf16(af, wf[nt][ks], acc[mt][nt], 0, 0, 0);
    }
  }

  // epilogue: two passes of 64 rows through fp32 LDS, then coalesced float4 stores
  float* const yout = out + (size_t)NB * 128;
  #pragma unroll
  for (int pass = 0; pass < 2; ++pass) {
    __syncthreads();
    if (mw == pass) {
      #pragma unroll
      for (int mt = 0; mt < 4; ++mt)
        #pragma unroll
        for (int nt = 0; nt < 5; ++nt) {
          const int rr = mt * 16 + ((lane >> 4) << 2);        // row within this 64-row pass
          const int cc = nw * 80 + nt * 16 + (lane & 15);
          #pragma unroll
          for (int i = 0; i < 4; ++i)
            fb[(rr + i) * 164 + cc] = acc[mt][nt][i];
        }
    }
    __syncthreads();
    const int rb = base + pass * 64;
    #pragma unroll
    for (int p = 0; p < 8; ++p) {   // dx: 64 rows x 128 cols fp32
      int g = p * 256 + tid; int r = g >> 5, c = g & 31;
      *(f4v*)&out[(size_t)(rb + r) * 128 + c * 4] = *(const f4v*)&fb[r * 164 + c * 4];
    }
    #pragma unroll
    for (int p = 0; p < 2; ++p) {   // y: 64 rows x 32 cols fp32
      int g = p * 256 + tid; int r = g >> 3, c = g & 7;
      *(f4v*)&yout[(size_t)(rb + r) * 32 + c * 4] = *(const f4v*)&fb[r * 164 + 128 + c * 4];
    }
  }
}

extern "C" void kernel_launch(void* const* d_in, const int* in_sizes, int n_in,
                              void* d_out, int out_size, void* d_ws, size_t ws_size,
                              hipStream_t stream) {
  // identify unambiguous inputs by element count (insurance against ordering surprises);
  // the three 128x128 matrices keep dict order Q,P,S per harness contract.
  const float *u = nullptr, *x = nullptr, *G = nullptr, *H = nullptr;
  const float* sq[3] = {nullptr, nullptr, nullptr};
  int nsq = 0;
  for (int i = 0; i < n_in; ++i) {
    const float* p = (const float*)d_in[i];
    switch (in_sizes[i]) {
      case NB * 64:  u = p; break;
      case NB * 128: x = p; break;
      case 32 * 128: G = p; break;
      case 128 * 64: H = p; break;
      case 128 * 128: if (nsq < 3) sq[nsq++] = p; break;
      default: break;
    }
  }
  const float* Q = sq[0];
  const float* P = sq[1];
  const float* S = sq[2];

  char* ws = (char*)d_ws;
  unsigned short* W = (unsigned short*)ws;        // 160*192 bf16 = 61440 B
  float* HtH = (float*)(ws + 61440);              // 64*64 fp32  = 16384 B
  float* Mf  = (float*)(ws + 77824);              // 128*128 fp32 = 65536 B
  float* out = (float*)d_out;

  k_prep1 <<<80,   256,  0, stream>>>(Q, S, G, H, Mf, HtH, W);
  k_prepAC<<<68,   256,  0, stream>>>(Mf, P, G, W);
  k_prep23<<<1,    1024, 0, stream>>>(Q, H, HtH, W);
  k_main  <<<2048, 256,  0, stream>>>(x, u, W, out);
}